// Round 1
// baseline (192.900 us; speedup 1.0000x reference)
//
#include <hip/hip_runtime.h>

// Model: enc linear(37->64)+relu -> BiLSTM(H=64, T=128, B=2048) -> (degenerate
// attention == sum over T) -> 10-step decoder LSTM with constant input -> softmax(11).
//
// Exploits: attention weights are all-ones (softmax over a size-1 axis), so
// fd[b] = sum_t concat(hf,hb)[b,t,:] and att1/att2 are dead. fd@dec_wih.T is
// hoisted out of the decoder loop.

typedef _Float16 f16;
typedef f16 f16x8 __attribute__((ext_vector_type(8)));
typedef float f32x4 __attribute__((ext_vector_type(4)));

#define MFMA16(a, b, c) __builtin_amdgcn_mfma_f32_16x16x32_f16(a, b, c, 0, 0, 0)

__device__ __forceinline__ float sigf(float x) { return 1.f / (1.f + __expf(-x)); }
__device__ __forceinline__ float tanhf_fast(float x) {
  float e = __expf(2.f * x);
  return 1.f - 2.f / (e + 1.f);   // exact at +/-inf, fine precision near 0
}

// e-fragment tensor layout (f16, 32 MB in d_ws):
//   addr16B = ((t*128 + bgroup)*2 + ksub)*64 + slot ; slot = (b&15) | (((k>>3)&3)<<4)
//   within-slot element i = k&7 ; k = ksub*32 + 8*(slot>>4) + i
// This is exactly the 16x16x32 MFMA B-fragment for B[k][b] = e[b][k].

// ---------------- Kernel A: e = relu(x @ W1^T + b1), emitted as fragments ----
__global__ __launch_bounds__(256) void enc_linear_k(
    const float* __restrict__ x, const float* __restrict__ w1,
    const float* __restrict__ b1, f16* __restrict__ efrag) {
  const int t = blockIdx.y;
  const int bblock = blockIdx.x;
  const int tid = threadIdx.x;
  const int w = tid >> 6, l = tid & 63;
  const int rho = l & 15, c = l >> 4;

  __shared__ float ldsw[64 * 37];
  __shared__ float ldsb[64];
  __shared__ __align__(16) f16 ldse[4][2][64][8];

  for (int i = tid; i < 64 * 37; i += 256) ldsw[i] = w1[i];
  if (tid < 64) ldsb[tid] = b1[tid];
  __syncthreads();

  // B-fragments of W1^T: B[d][kout] = W1[kout][d], K padded 37 -> 64 with zeros
  f16x8 bw[4][2];
#pragma unroll
  for (int nt = 0; nt < 4; nt++) {
    const int kout = nt * 16 + rho;
#pragma unroll
    for (int ks = 0; ks < 2; ks++) {
      f16x8 v;
#pragma unroll
      for (int i = 0; i < 8; i++) {
        const int d = ks * 32 + c * 8 + i;
        v[i] = (f16)(d < 37 ? ldsw[kout * 37 + d] : 0.f);
      }
      bw[nt][ks] = v;
    }
  }

  // A-fragments: rows = 16 batch elements at this t
  const int brow = bblock * 64 + w * 16 + rho;
  const float* xrow = x + ((size_t)brow * 128 + t) * 37;
  f16x8 a0, a1;
#pragma unroll
  for (int i = 0; i < 8; i++) a0[i] = (f16)xrow[c * 8 + i];
#pragma unroll
  for (int i = 0; i < 8; i++) {
    const int d = 32 + c * 8 + i;
    a1[i] = (f16)((c == 0 && d < 37) ? xrow[d] : 0.f);
  }

  f32x4 acc[4] = {};
#pragma unroll
  for (int nt = 0; nt < 4; nt++) {
    acc[nt] = MFMA16(a0, bw[nt][0], acc[nt]);
    acc[nt] = MFMA16(a1, bw[nt][1], acc[nt]);
  }

  // epilogue: +bias, relu, to fragment layout in LDS, then coalesced store
#pragma unroll
  for (int nt = 0; nt < 4; nt++) {
    const int k = nt * 16 + rho;
#pragma unroll
    for (int r = 0; r < 4; r++) {
      const int bi = c * 4 + r;  // b & 15  (C/D: row = 4*(l>>4)+r, col = l&15)
      float v = acc[nt][r] + ldsb[k];
      v = fmaxf(v, 0.f);
      ldse[w][k >> 5][bi | (((k >> 3) & 3) << 4)][k & 7] = (f16)v;
    }
  }
  __syncthreads();
  const int bg = bblock * 4 + w;
  float4* dst = (float4*)efrag + ((size_t)(t * 128 + bg) * 2) * 64;
  const float4* src = (const float4*)&ldse[w][0][0][0];
  dst[l] = src[l];
  dst[64 + l] = src[64 + l];
}

// ---------------- Kernel B: BiLSTM, fd accumulation ----------------
// gates^T = Wperm @ [e|h]^T : gate-interleaved row permutation puts all 4 gates
// of cell (b, j) into one lane's 4 accumulator regs -> in-lane LSTM update.
__global__ __launch_bounds__(256) void bilstm_k(
    const f16* __restrict__ efrag,
    const float* __restrict__ wih_f, const float* __restrict__ whh_f,
    const float* __restrict__ bih_f, const float* __restrict__ bhh_f,
    const float* __restrict__ wih_b, const float* __restrict__ whh_b,
    const float* __restrict__ bih_b, const float* __restrict__ bhh_b,
    float* __restrict__ fd) {
  const int bid = blockIdx.x;
  const int dir = bid >> 7;
  const int bg = bid & 127;
  const int tid = threadIdx.x;
  const int w = tid >> 6, l = tid & 63;
  const int rho = l & 15, c = l >> 4;
  const int gate = rho & 3, uoff = rho >> 2;

  const float* wih = dir ? wih_b : wih_f;
  const float* whh = dir ? whh_b : whh_f;
  const float* bih = dir ? bih_b : bih_f;
  const float* bhh = dir ? bhh_b : bhh_f;

  __shared__ __align__(16) f16 hbuf[2][2][64][8];
  {
    int* hz = (int*)hbuf;
    for (int i = tid; i < (int)(sizeof(hbuf) / 4); i += 256) hz[i] = 0;
  }

  // Permuted-weight A-fragments (kept in registers for all 128 steps).
  // m-tile m=4w+q covers gate-rows 16m..16m+15; row rho -> original W row
  // n = 64*gate + (4m + uoff)  (unit j = 4m+uoff, gate = rho&3).
  f16x8 aih[4][2], ahh[4][2];
#pragma unroll
  for (int q = 0; q < 4; q++) {
    const int m = 4 * w + q;
    const int n = gate * 64 + 4 * m + uoff;
#pragma unroll
    for (int ks = 0; ks < 2; ks++) {
      const float* p1 = wih + n * 64 + ks * 32 + c * 8;
      const float* p2 = whh + n * 64 + ks * 32 + c * 8;
      f16x8 v1, v2;
#pragma unroll
      for (int i = 0; i < 8; i++) { v1[i] = (f16)p1[i]; v2[i] = (f16)p2[i]; }
      aih[q][ks] = v1;
      ahh[q][ks] = v2;
    }
  }
  // Per-lane bias: acc reg r of m-tile q is gate r of unit j = 16w+4q+c.
  f32x4 bias[4];
#pragma unroll
  for (int q = 0; q < 4; q++) {
    const int j = 16 * w + 4 * q + c;
#pragma unroll
    for (int r = 0; r < 4; r++) bias[q][r] = bih[64 * r + j] + bhh[64 * r + j];
  }

  const f16x8* eb = (const f16x8*)efrag;
  const int tm0 = dir ? 127 : 0;
  const size_t idx0 = ((size_t)(tm0 * 128 + bg) * 2) * 64 + l;
  f16x8 ec0 = eb[idx0], ec1 = eb[idx0 + 64];
  f16x8 en0 = ec0, en1 = ec1;

  float cst[4] = {0.f, 0.f, 0.f, 0.f};
  float hs[4] = {0.f, 0.f, 0.f, 0.f};

  __syncthreads();  // hbuf zeros visible

  for (int t = 0; t < 128; t++) {
    if (t + 1 < 128) {  // register-prefetch next e-fragments
      const int tm = dir ? 127 - (t + 1) : t + 1;
      const size_t idx = ((size_t)(tm * 128 + bg) * 2) * 64 + l;
      en0 = eb[idx];
      en1 = eb[idx + 64];
    }
    const int cur = t & 1;
    f16x8 h0 = *(const f16x8*)&hbuf[cur][0][l][0];
    f16x8 h1 = *(const f16x8*)&hbuf[cur][1][l][0];
    f32x4 acc[4];
#pragma unroll
    for (int q = 0; q < 4; q++) {
      f32x4 a = bias[q];
      a = MFMA16(aih[q][0], ec0, a);
      a = MFMA16(aih[q][1], ec1, a);
      a = MFMA16(ahh[q][0], h0, a);
      a = MFMA16(ahh[q][1], h1, a);
      acc[q] = a;
    }
#pragma unroll
    for (int q = 0; q < 4; q++) {
      const float ig = sigf(acc[q][0]);
      const float fg = sigf(acc[q][1]);
      const float gg = tanhf_fast(acc[q][2]);
      const float og = sigf(acc[q][3]);
      cst[q] = fg * cst[q] + ig * gg;
      const float h = og * tanhf_fast(cst[q]);
      hs[q] += h;  // fd accumulation (sum over t; reversal irrelevant)
      const int j = 16 * w + 4 * q + c;
      hbuf[cur ^ 1][j >> 5][rho | (((j >> 3) & 3) << 4)][j & 7] = (f16)h;
    }
    ec0 = en0;
    ec1 = en1;
    __syncthreads();
  }
#pragma unroll
  for (int q = 0; q < 4; q++) {
    const int j = 16 * w + 4 * q + c;
    fd[(size_t)(bg * 16 + rho) * 128 + dir * 64 + j] = hs[q];
  }
}

// ---------------- Kernel C: decoder (10 steps, constant input fd) -----------
__global__ __launch_bounds__(256) void decoder_k(
    const float* __restrict__ fd,
    const float* __restrict__ dwih, const float* __restrict__ dwhh,
    const float* __restrict__ dbih, const float* __restrict__ dbhh,
    const float* __restrict__ dlw, const float* __restrict__ dlb,
    const int* __restrict__ outlen_p, float* __restrict__ out) {
  const int b0 = blockIdx.x * 16;
  const int tid = threadIdx.x;
  const int w = tid >> 6, l = tid & 63;
  const int rho = l & 15, c = l >> 4;
  const int gate = rho & 3, uoff = rho >> 2;
  const int outlen = *outlen_p;

  __shared__ __align__(16) f16 hbuf[2][2][64][8];
  __shared__ float h32[64][16];
  __shared__ float ldslw[11 * 64];
  __shared__ float ldslb[16];
  __shared__ float lg[16][16];

  {
    int* hz = (int*)hbuf;
    for (int i = tid; i < (int)(sizeof(hbuf) / 4); i += 256) hz[i] = 0;
  }
  for (int i = tid; i < 704; i += 256) ldslw[i] = dlw[i];
  if (tid < 16) ldslb[tid] = (tid < 11) ? dlb[tid] : 0.f;

  f16x8 awhh[4][2];
  f32x4 acc0[4];  // bias + fd @ dec_wih^T : constant across steps
  {
    f16x8 bfd[4];
#pragma unroll
    for (int ks = 0; ks < 4; ks++) {
      const float* p = fd + (size_t)(b0 + rho) * 128 + ks * 32 + c * 8;
      f16x8 v;
#pragma unroll
      for (int i = 0; i < 8; i++) v[i] = (f16)p[i];
      bfd[ks] = v;
    }
#pragma unroll
    for (int q = 0; q < 4; q++) {
      const int m = 4 * w + q;
      const int n = gate * 64 + 4 * m + uoff;
      f32x4 a;
      const int j = 16 * w + 4 * q + c;
#pragma unroll
      for (int r = 0; r < 4; r++) a[r] = dbih[64 * r + j] + dbhh[64 * r + j];
#pragma unroll
      for (int ks = 0; ks < 4; ks++) {
        const float* p = dwih + n * 128 + ks * 32 + c * 8;
        f16x8 v;
#pragma unroll
        for (int i = 0; i < 8; i++) v[i] = (f16)p[i];
        a = MFMA16(v, bfd[ks], a);
      }
      acc0[q] = a;
#pragma unroll
      for (int ks = 0; ks < 2; ks++) {
        const float* p = dwhh + n * 64 + ks * 32 + c * 8;
        f16x8 v;
#pragma unroll
        for (int i = 0; i < 8; i++) v[i] = (f16)p[i];
        awhh[q][ks] = v;
      }
    }
  }
  float cst[4] = {0.f, 0.f, 0.f, 0.f};
  __syncthreads();

  for (int s = 0; s < outlen; s++) {
    const int cur = s & 1;
    f16x8 h0 = *(const f16x8*)&hbuf[cur][0][l][0];
    f16x8 h1 = *(const f16x8*)&hbuf[cur][1][l][0];
#pragma unroll
    for (int q = 0; q < 4; q++) {
      f32x4 a = acc0[q];
      a = MFMA16(awhh[q][0], h0, a);
      a = MFMA16(awhh[q][1], h1, a);
      const float ig = sigf(a[0]);
      const float fg = sigf(a[1]);
      const float gg = tanhf_fast(a[2]);
      const float og = sigf(a[3]);
      cst[q] = fg * cst[q] + ig * gg;
      const float h = og * tanhf_fast(cst[q]);
      const int j = 16 * w + 4 * q + c;
      hbuf[cur ^ 1][j >> 5][rho | (((j >> 3) & 3) << 4)][j & 7] = (f16)h;
      h32[j][rho] = h;
    }
    __syncthreads();
    const int b = tid >> 4, o = tid & 15;
    float logit = 0.f;
    if (o < 11) {
      logit = ldslb[o];
      for (int j = 0; j < 64; j++) logit += h32[j][b] * ldslw[o * 64 + j];
      lg[b][o] = logit;
    }
    __syncthreads();
    if (o < 11) {
      float mx = lg[b][0];
      for (int k = 1; k < 11; k++) mx = fmaxf(mx, lg[b][k]);
      float sum = 0.f;
      for (int k = 0; k < 11; k++) sum += __expf(lg[b][k] - mx);
      out[(size_t)(b0 + b) * outlen * 11 + (size_t)s * 11 + o] =
          __expf(logit - mx) / sum;
    }
    __syncthreads();
  }
}

extern "C" void kernel_launch(void* const* d_in, const int* in_sizes, int n_in,
                              void* d_out, int out_size, void* d_ws, size_t ws_size,
                              hipStream_t stream) {
  const float* x = (const float*)d_in[0];
  const float* w1 = (const float*)d_in[1];
  const float* b1 = (const float*)d_in[2];
  const float* wih_f = (const float*)d_in[3];
  const float* whh_f = (const float*)d_in[4];
  const float* bih_f = (const float*)d_in[5];
  const float* bhh_f = (const float*)d_in[6];
  const float* wih_b = (const float*)d_in[7];
  const float* whh_b = (const float*)d_in[8];
  const float* bih_b = (const float*)d_in[9];
  const float* bhh_b = (const float*)d_in[10];
  // d_in[11..14]: attention weights — provably dead (softmax over size-1 axis)
  const float* dwih = (const float*)d_in[15];
  const float* dwhh = (const float*)d_in[16];
  const float* dbih = (const float*)d_in[17];
  const float* dbhh = (const float*)d_in[18];
  const float* dlw = (const float*)d_in[19];
  const float* dlb = (const float*)d_in[20];
  const int* outlen = (const int*)d_in[21];
  float* out = (float*)d_out;

  f16* efrag = (f16*)d_ws;                              // 32 MB
  float* fd = (float*)((char*)d_ws + (size_t)33554432); // 1 MB

  hipLaunchKernelGGL(enc_linear_k, dim3(32, 128), dim3(256), 0, stream,
                     x, w1, b1, efrag);
  hipLaunchKernelGGL(bilstm_k, dim3(256), dim3(256), 0, stream,
                     efrag, wih_f, whh_f, bih_f, bhh_f,
                     wih_b, whh_b, bih_b, bhh_b, fd);
  hipLaunchKernelGGL(decoder_k, dim3(128), dim3(256), 0, stream,
                     fd, dwih, dwhh, dbih, dbhh, dlw, dlb, outlen, out);
}

// Round 2
// 126.882 us; speedup vs baseline: 1.5203x; 1.5203x over previous
//
#include <hip/hip_runtime.h>

// Model: enc linear(37->64)+relu -> BiLSTM(H=64, T=128, B=2048) -> (degenerate
// attention == sum over T) -> 10-step decoder LSTM with constant input -> softmax(11).
//
// Exploits: attention weights are all-ones (softmax over a size-1 axis), so
// fd[b] = sum_t concat(hf,hb)[b,t,:] and att1/att2 are dead. fd@dec_wih.T is
// hoisted out of the decoder loop.
//
// R2: bilstm_k 512 threads (8 waves, 2 m-tiles/wave -> 2 waves/SIMD for latency
// overlap), exp2-folded gate scales (sig/tanh = rcp(1+exp2(acc))), and a raw
// lgkmcnt-only barrier so e-prefetch loads stay in flight across steps.

typedef _Float16 f16;
typedef f16 f16x8 __attribute__((ext_vector_type(8)));
typedef float f32x4 __attribute__((ext_vector_type(4)));

#define MFMA16(a, b, c) __builtin_amdgcn_mfma_f32_16x16x32_f16(a, b, c, 0, 0, 0)

__device__ __forceinline__ float sigf(float x) { return 1.f / (1.f + __expf(-x)); }
__device__ __forceinline__ float tanhf_fast(float x) {
  float e = __expf(2.f * x);
  return 1.f - 2.f / (e + 1.f);
}

// gate scales folded into weights: i,f,o -> -log2e ; g -> -2*log2e
// then sig = rcp(1+exp2(y)), tanh = 2*rcp(1+exp2(y)) - 1.
#define NLOG2E  -1.4426950408889634f
#define N2LOG2E -2.8853900817779268f

__device__ __forceinline__ float rcp_(float x) { return __builtin_amdgcn_rcpf(x); }
__device__ __forceinline__ float ex2_(float x) { return __builtin_amdgcn_exp2f(x); }

// e-fragment tensor layout (f16, 32 MB in d_ws):
//   addr16B = ((t*128 + bgroup)*2 + ksub)*64 + slot ; slot = (b&15) | (((k>>3)&3)<<4)
//   within-slot element i = k&7 ; k = ksub*32 + 8*(slot>>4) + i
// This is exactly the 16x16x32 MFMA B-fragment for B[k][b] = e[b][k].

// ---------------- Kernel A: e = relu(x @ W1^T + b1), emitted as fragments ----
__global__ __launch_bounds__(256) void enc_linear_k(
    const float* __restrict__ x, const float* __restrict__ w1,
    const float* __restrict__ b1, f16* __restrict__ efrag) {
  const int t = blockIdx.y;
  const int bblock = blockIdx.x;
  const int tid = threadIdx.x;
  const int w = tid >> 6, l = tid & 63;
  const int rho = l & 15, c = l >> 4;

  __shared__ float ldsw[64 * 37];
  __shared__ float ldsb[64];
  __shared__ __align__(16) f16 ldse[4][2][64][8];

  for (int i = tid; i < 64 * 37; i += 256) ldsw[i] = w1[i];
  if (tid < 64) ldsb[tid] = b1[tid];
  __syncthreads();

  // B-fragments of W1^T: B[d][kout] = W1[kout][d], K padded 37 -> 64 with zeros
  f16x8 bw[4][2];
#pragma unroll
  for (int nt = 0; nt < 4; nt++) {
    const int kout = nt * 16 + rho;
#pragma unroll
    for (int ks = 0; ks < 2; ks++) {
      f16x8 v;
#pragma unroll
      for (int i = 0; i < 8; i++) {
        const int d = ks * 32 + c * 8 + i;
        v[i] = (f16)(d < 37 ? ldsw[kout * 37 + d] : 0.f);
      }
      bw[nt][ks] = v;
    }
  }

  // A-fragments: rows = 16 batch elements at this t
  const int brow = bblock * 64 + w * 16 + rho;
  const float* xrow = x + ((size_t)brow * 128 + t) * 37;
  f16x8 a0, a1;
#pragma unroll
  for (int i = 0; i < 8; i++) a0[i] = (f16)xrow[c * 8 + i];
#pragma unroll
  for (int i = 0; i < 8; i++) {
    const int d = 32 + c * 8 + i;
    a1[i] = (f16)((c == 0 && d < 37) ? xrow[d] : 0.f);
  }

  f32x4 acc[4] = {};
#pragma unroll
  for (int nt = 0; nt < 4; nt++) {
    acc[nt] = MFMA16(a0, bw[nt][0], acc[nt]);
    acc[nt] = MFMA16(a1, bw[nt][1], acc[nt]);
  }

  // epilogue: +bias, relu, to fragment layout in LDS, then coalesced store
#pragma unroll
  for (int nt = 0; nt < 4; nt++) {
    const int k = nt * 16 + rho;
#pragma unroll
    for (int r = 0; r < 4; r++) {
      const int bi = c * 4 + r;  // b & 15  (C/D: row = 4*(l>>4)+r, col = l&15)
      float v = acc[nt][r] + ldsb[k];
      v = fmaxf(v, 0.f);
      ldse[w][k >> 5][bi | (((k >> 3) & 3) << 4)][k & 7] = (f16)v;
    }
  }
  __syncthreads();
  const int bg = bblock * 4 + w;
  float4* dst = (float4*)efrag + ((size_t)(t * 128 + bg) * 2) * 64;
  const float4* src = (const float4*)&ldse[w][0][0][0];
  dst[l] = src[l];
  dst[64 + l] = src[64 + l];
}

// ---------------- Kernel B: BiLSTM, fd accumulation ----------------
// 8 waves/block (512 thr): wave w owns m-tiles {2w, 2w+1}; gate-interleaved row
// permutation puts all 4 gates of cell (b, j) into one lane's 4 acc regs.
__global__ __launch_bounds__(512, 2) void bilstm_k(
    const f16* __restrict__ efrag,
    const float* __restrict__ wih_f, const float* __restrict__ whh_f,
    const float* __restrict__ bih_f, const float* __restrict__ bhh_f,
    const float* __restrict__ wih_b, const float* __restrict__ whh_b,
    const float* __restrict__ bih_b, const float* __restrict__ bhh_b,
    float* __restrict__ fd) {
  const int bid = blockIdx.x;
  const int dir = bid >> 7;
  const int bg = bid & 127;
  const int tid = threadIdx.x;
  const int w = tid >> 6, l = tid & 63;      // w in [0,8)
  const int rho = l & 15, c = l >> 4;
  const int gate = rho & 3, uoff = rho >> 2;

  const float* wih = dir ? wih_b : wih_f;
  const float* whh = dir ? whh_b : whh_f;
  const float* bih = dir ? bih_b : bih_f;
  const float* bhh = dir ? bhh_b : bhh_f;

  __shared__ __align__(16) f16 hbuf[2][2][64][8];
  {
    int* hz = (int*)hbuf;
    for (int i = tid; i < (int)(sizeof(hbuf) / 4); i += 512) hz[i] = 0;
  }

  // Row scale by gate (exp2 folding): rows of gate g scaled by SG[g].
  const float sA = (gate == 2) ? N2LOG2E : NLOG2E;

  // Permuted-weight A-fragments, registers for all 128 steps.
  // m-tile m = 2w+q; fragment row rho -> original W row n = 64*gate + 4m + uoff.
  f16x8 aih[2][2], ahh[2][2];
#pragma unroll
  for (int q = 0; q < 2; q++) {
    const int m = 2 * w + q;
    const int n = gate * 64 + 4 * m + uoff;
#pragma unroll
    for (int ks = 0; ks < 2; ks++) {
      const float* p1 = wih + n * 64 + ks * 32 + c * 8;
      const float* p2 = whh + n * 64 + ks * 32 + c * 8;
      f16x8 v1, v2;
#pragma unroll
      for (int i = 0; i < 8; i++) {
        v1[i] = (f16)(p1[i] * sA);
        v2[i] = (f16)(p2[i] * sA);
      }
      aih[q][ks] = v1;
      ahh[q][ks] = v2;
    }
  }
  // Per-lane bias: acc reg r of m-tile q is gate r of unit j = 8w + 4q + c.
  f32x4 bias[2];
#pragma unroll
  for (int q = 0; q < 2; q++) {
    const int j = 8 * w + 4 * q + c;
#pragma unroll
    for (int r = 0; r < 4; r++) {
      const float sr = (r == 2) ? N2LOG2E : NLOG2E;
      bias[q][r] = (bih[64 * r + j] + bhh[64 * r + j]) * sr;
    }
  }

  const f16x8* eb = (const f16x8*)efrag;
  const int tm0 = dir ? 127 : 0;
  const size_t idx0 = ((size_t)(tm0 * 128 + bg) * 2) * 64 + l;
  f16x8 ec0 = eb[idx0], ec1 = eb[idx0 + 64];
  f16x8 en0 = ec0, en1 = ec1;

  float cst[2] = {0.f, 0.f};
  float hs[2] = {0.f, 0.f};

  __syncthreads();  // hbuf zeros visible

  for (int t = 0; t < 128; t++) {
    if (t + 1 < 128) {  // register-prefetch next e-fragments
      const int tm = dir ? 127 - (t + 1) : t + 1;
      const size_t idx = ((size_t)(tm * 128 + bg) * 2) * 64 + l;
      en0 = eb[idx];
      en1 = eb[idx + 64];
    }
    const int cur = t & 1;
    f16x8 h0 = *(const f16x8*)&hbuf[cur][0][l][0];
    f16x8 h1 = *(const f16x8*)&hbuf[cur][1][l][0];
#pragma unroll
    for (int q = 0; q < 2; q++) {
      f32x4 a = bias[q];
      a = MFMA16(aih[q][0], ec0, a);
      a = MFMA16(aih[q][1], ec1, a);
      a = MFMA16(ahh[q][0], h0, a);
      a = MFMA16(ahh[q][1], h1, a);
      // pointwise: sig = rcp(1+exp2(y)), tanh = 2*rcp(1+exp2(y)) - 1
      const float ig = rcp_(1.f + ex2_(a[0]));
      const float fg = rcp_(1.f + ex2_(a[1]));
      const float gg = 2.f * rcp_(1.f + ex2_(a[2])) - 1.f;
      const float og = rcp_(1.f + ex2_(a[3]));
      cst[q] = fg * cst[q] + ig * gg;
      const float th = 2.f * rcp_(1.f + ex2_(cst[q] * N2LOG2E)) - 1.f;
      const float h = og * th;
      hs[q] += h;  // fd accumulation (sum over t; reversal irrelevant)
      const int j = 8 * w + 4 * q + c;
      hbuf[cur ^ 1][j >> 5][rho | (((j >> 3) & 3) << 4)][j & 7] = (f16)h;
    }
    ec0 = en0;
    ec1 = en1;
    // lgkm-only barrier: h-exchange through LDS must drain; keep the global
    // e-prefetch (vmcnt) in flight across the step boundary.
    asm volatile("s_waitcnt lgkmcnt(0)\n\ts_barrier" ::: "memory");
  }
#pragma unroll
  for (int q = 0; q < 2; q++) {
    const int j = 8 * w + 4 * q + c;
    fd[(size_t)(bg * 16 + rho) * 128 + dir * 64 + j] = hs[q];
  }
}

// ---------------- Kernel C: decoder (10 steps, constant input fd) -----------
__global__ __launch_bounds__(256) void decoder_k(
    const float* __restrict__ fd,
    const float* __restrict__ dwih, const float* __restrict__ dwhh,
    const float* __restrict__ dbih, const float* __restrict__ dbhh,
    const float* __restrict__ dlw, const float* __restrict__ dlb,
    const int* __restrict__ outlen_p, float* __restrict__ out) {
  const int b0 = blockIdx.x * 16;
  const int tid = threadIdx.x;
  const int w = tid >> 6, l = tid & 63;
  const int rho = l & 15, c = l >> 4;
  const int gate = rho & 3, uoff = rho >> 2;
  const int outlen = *outlen_p;

  __shared__ __align__(16) f16 hbuf[2][2][64][8];
  __shared__ float h32[64][16];
  __shared__ float ldslw[11 * 64];
  __shared__ float ldslb[16];
  __shared__ float lg[16][16];

  {
    int* hz = (int*)hbuf;
    for (int i = tid; i < (int)(sizeof(hbuf) / 4); i += 256) hz[i] = 0;
  }
  for (int i = tid; i < 704; i += 256) ldslw[i] = dlw[i];
  if (tid < 16) ldslb[tid] = (tid < 11) ? dlb[tid] : 0.f;

  f16x8 awhh[4][2];
  f32x4 acc0[4];  // bias + fd @ dec_wih^T : constant across steps
  {
    f16x8 bfd[4];
#pragma unroll
    for (int ks = 0; ks < 4; ks++) {
      const float* p = fd + (size_t)(b0 + rho) * 128 + ks * 32 + c * 8;
      f16x8 v;
#pragma unroll
      for (int i = 0; i < 8; i++) v[i] = (f16)p[i];
      bfd[ks] = v;
    }
#pragma unroll
    for (int q = 0; q < 4; q++) {
      const int m = 4 * w + q;
      const int n = gate * 64 + 4 * m + uoff;
      f32x4 a;
      const int j = 16 * w + 4 * q + c;
#pragma unroll
      for (int r = 0; r < 4; r++) a[r] = dbih[64 * r + j] + dbhh[64 * r + j];
#pragma unroll
      for (int ks = 0; ks < 4; ks++) {
        const float* p = dwih + n * 128 + ks * 32 + c * 8;
        f16x8 v;
#pragma unroll
        for (int i = 0; i < 8; i++) v[i] = (f16)p[i];
        a = MFMA16(v, bfd[ks], a);
      }
      acc0[q] = a;
#pragma unroll
      for (int ks = 0; ks < 2; ks++) {
        const float* p = dwhh + n * 64 + ks * 32 + c * 8;
        f16x8 v;
#pragma unroll
        for (int i = 0; i < 8; i++) v[i] = (f16)p[i];
        awhh[q][ks] = v;
      }
    }
  }
  float cst[4] = {0.f, 0.f, 0.f, 0.f};
  __syncthreads();

  for (int s = 0; s < outlen; s++) {
    const int cur = s & 1;
    f16x8 h0 = *(const f16x8*)&hbuf[cur][0][l][0];
    f16x8 h1 = *(const f16x8*)&hbuf[cur][1][l][0];
#pragma unroll
    for (int q = 0; q < 4; q++) {
      f32x4 a = acc0[q];
      a = MFMA16(awhh[q][0], h0, a);
      a = MFMA16(awhh[q][1], h1, a);
      const float ig = sigf(a[0]);
      const float fg = sigf(a[1]);
      const float gg = tanhf_fast(a[2]);
      const float og = sigf(a[3]);
      cst[q] = fg * cst[q] + ig * gg;
      const float h = og * tanhf_fast(cst[q]);
      const int j = 16 * w + 4 * q + c;
      hbuf[cur ^ 1][j >> 5][rho | (((j >> 3) & 3) << 4)][j & 7] = (f16)h;
      h32[j][rho] = h;
    }
    __syncthreads();
    const int b = tid >> 4, o = tid & 15;
    float logit = 0.f;
    if (o < 11) {
      logit = ldslb[o];
      for (int j = 0; j < 64; j++) logit += h32[j][b] * ldslw[o * 64 + j];
      lg[b][o] = logit;
    }
    __syncthreads();
    if (o < 11) {
      float mx = lg[b][0];
      for (int k = 1; k < 11; k++) mx = fmaxf(mx, lg[b][k]);
      float sum = 0.f;
      for (int k = 0; k < 11; k++) sum += __expf(lg[b][k] - mx);
      out[(size_t)(b0 + b) * outlen * 11 + (size_t)s * 11 + o] =
          __expf(logit - mx) / sum;
    }
    __syncthreads();
  }
}

extern "C" void kernel_launch(void* const* d_in, const int* in_sizes, int n_in,
                              void* d_out, int out_size, void* d_ws, size_t ws_size,
                              hipStream_t stream) {
  const float* x = (const float*)d_in[0];
  const float* w1 = (const float*)d_in[1];
  const float* b1 = (const float*)d_in[2];
  const float* wih_f = (const float*)d_in[3];
  const float* whh_f = (const float*)d_in[4];
  const float* bih_f = (const float*)d_in[5];
  const float* bhh_f = (const float*)d_in[6];
  const float* wih_b = (const float*)d_in[7];
  const float* whh_b = (const float*)d_in[8];
  const float* bih_b = (const float*)d_in[9];
  const float* bhh_b = (const float*)d_in[10];
  // d_in[11..14]: attention weights — provably dead (softmax over size-1 axis)
  const float* dwih = (const float*)d_in[15];
  const float* dwhh = (const float*)d_in[16];
  const float* dbih = (const float*)d_in[17];
  const float* dbhh = (const float*)d_in[18];
  const float* dlw = (const float*)d_in[19];
  const float* dlb = (const float*)d_in[20];
  const int* outlen = (const int*)d_in[21];
  float* out = (float*)d_out;

  f16* efrag = (f16*)d_ws;                              // 32 MB
  float* fd = (float*)((char*)d_ws + (size_t)33554432); // 1 MB

  hipLaunchKernelGGL(enc_linear_k, dim3(32, 128), dim3(256), 0, stream,
                     x, w1, b1, efrag);
  hipLaunchKernelGGL(bilstm_k, dim3(256), dim3(512), 0, stream,
                     efrag, wih_f, whh_f, bih_f, bhh_f,
                     wih_b, whh_b, bih_b, bhh_b, fd);
  hipLaunchKernelGGL(decoder_k, dim3(128), dim3(256), 0, stream,
                     fd, dwih, dwhh, dbih, dbhh, dlw, dlb, outlen, out);
}